// Round 2
// baseline (1343.650 us; speedup 1.0000x reference)
//
#include <hip/hip_runtime.h>

// WaveFDTD2D: p_new = 2p - p_old + v^2*dt^2 * lap(p), zero-padded 5-point
// Laplacian, source add AFTER stencil, receivers sampled AFTER source add.
// Output: out[r*NSTEPS + t] (seismogram transposed).
//
// Round 2: fix receiver gather — block is (64,4), so flatten thread id to
// cover all 128 receivers (round 1 only gathered 0..63; absmax was exactly
// half of max|ref|).

#define NXg 512
#define NZg 512
#define NSTEPSg 512
#define NRECg 128
#define DT2f 1.0e-6f
#define INV_DXDZf 1.0e-2f

__global__ __launch_bounds__(256) void fdtd_init_v2(const float* __restrict__ vel,
                                                    float* __restrict__ v2dt2) {
    int i = blockIdx.x * blockDim.x + threadIdx.x;
    if (i < NXg * NZg) {
        float v = vel[i];
        v2dt2[i] = v * v * DT2f;
    }
}

__global__ __launch_bounds__(256) void fdtd_step(const float* __restrict__ p_cur,
                                                 const float* __restrict__ p_old,
                                                 float* __restrict__ p_new,
                                                 const float* __restrict__ v2dt2,
                                                 const float* __restrict__ source,
                                                 const int* __restrict__ src_x,
                                                 const int* __restrict__ src_z,
                                                 const int* __restrict__ rec_x,
                                                 const int* __restrict__ rec_z,
                                                 float* __restrict__ out,
                                                 int t) {
    // Gather receivers for the PREVIOUS step's result (p_cur == p_new of t-1).
    // p_cur is read-only in this kernel, so this is race-free. Block is
    // (64,4): flatten thread id to cover all 128 receivers.
    if (t > 0 && blockIdx.x == 0 && blockIdx.y == 0) {
        int r = threadIdx.y * 64 + threadIdx.x;
        if (r < NRECg) {
            out[r * NSTEPSg + (t - 1)] = p_cur[rec_x[r] * NZg + rec_z[r]];
        }
    }

    int z = blockIdx.x * blockDim.x + threadIdx.x;  // contiguous dim
    int x = blockIdx.y * blockDim.y + threadIdx.y;
    int idx = x * NZg + z;

    float pc = p_cur[idx];
    float up = (x > 0)       ? p_cur[idx - NZg] : 0.0f;
    float dn = (x < NXg - 1) ? p_cur[idx + NZg] : 0.0f;
    float lf = (z > 0)       ? p_cur[idx - 1]   : 0.0f;
    float rt = (z < NZg - 1) ? p_cur[idx + 1]   : 0.0f;

    float lap = (up + dn + lf + rt - 4.0f * pc) * INV_DXDZf;
    float pn = 2.0f * pc - p_old[idx] + v2dt2[idx] * lap;
    if (x == *src_x && z == *src_z) pn += source[t] * DT2f;
    p_new[idx] = pn;
}

__global__ void fdtd_gather_last(const float* __restrict__ p_cur,
                                 const int* __restrict__ rec_x,
                                 const int* __restrict__ rec_z,
                                 float* __restrict__ out) {
    int r = threadIdx.x;
    if (r < NRECg) {
        out[r * NSTEPSg + (NSTEPSg - 1)] = p_cur[rec_x[r] * NZg + rec_z[r]];
    }
}

extern "C" void kernel_launch(void* const* d_in, const int* in_sizes, int n_in,
                              void* d_out, int out_size, void* d_ws, size_t ws_size,
                              hipStream_t stream) {
    const float* vel    = (const float*)d_in[0];
    const float* source = (const float*)d_in[1];
    const int*   src_x  = (const int*)d_in[2];
    const int*   src_z  = (const int*)d_in[3];
    const int*   rec_x  = (const int*)d_in[4];
    const int*   rec_z  = (const int*)d_in[5];
    float* out = (float*)d_out;

    float* pA = (float*)d_ws;
    float* pB = pA + NXg * NZg;
    float* v2 = pB + NXg * NZg;

    // ws is poisoned 0xAA before every timed launch: zero the two wavefields.
    hipMemsetAsync(pA, 0, (size_t)2 * NXg * NZg * sizeof(float), stream);
    fdtd_init_v2<<<(NXg * NZg + 255) / 256, 256, 0, stream>>>(vel, v2);

    dim3 block(64, 4);
    dim3 grid(NZg / 64, NXg / 4);

    float* cur = pA;  // zeros
    float* old = pB;  // zeros
    for (int t = 0; t < NSTEPSg; ++t) {
        // p_new overwrites old's buffer, then roles swap.
        fdtd_step<<<grid, block, 0, stream>>>(cur, old, old, v2, source,
                                              src_x, src_z, rec_x, rec_z, out, t);
        float* tmp = cur; cur = old; old = tmp;
    }
    fdtd_gather_last<<<1, 128, 0, stream>>>(cur, rec_x, rec_z, out);
}

// Round 3
// 955.495 us; speedup vs baseline: 1.4062x; 1.4062x over previous
//
#include <hip/hip_runtime.h>

// WaveFDTD2D, temporally-blocked: T=16 steps per launch, 32 launches.
// Each block: 32x32 interior, 64x64 extended LDS region (halo 16).
// Valid region shrinks 1 cell/side/step; after 16 steps it equals the
// interior. Register-resident own-cell state (cur/old/v2dt2); LDS ping-pong
// holds the neighbor field. Global ping-pong (set A/B) across launches
// avoids intra-launch tile read/write races. Exact L1 cone skip (cross
// stencil spreads 1 cell/step in L1) zeroes untouched receivers cheaply.

#define NXd 512
#define NZd 512
#define NSTEPSd 512
#define NRECd 128
#define DT2f 1.0e-6f
#define INVf 1.0e-2f
#define TBk 16           // temporal block (steps per launch)
#define TIk 32           // tile interior
#define EXTk 64          // TIk + 2*TBk
#define NTILEk 16        // NXd / TIk

__global__ __launch_bounds__(256) void fdtd_tblock(
    const float* __restrict__ vel,
    const float* __restrict__ source,
    const int* __restrict__ src_x, const int* __restrict__ src_z,
    const int* __restrict__ rec_x, const int* __restrict__ rec_z,
    const float* __restrict__ Gc_in, const float* __restrict__ Go_in,
    float* __restrict__ Gc_out, float* __restrict__ Go_out,
    float* __restrict__ out, int t0)
{
    __shared__ float sb[2][EXTk * EXTk];

    const int tid = threadIdx.x;
    const int r0 = tid >> 6;        // 0..3: row group
    const int ez = tid & 63;        // ext z coord
    const int gx0 = blockIdx.y * TIk, gz0 = blockIdx.x * TIk;
    const int ox = gx0 - TBk, oz = gz0 - TBk;

    const int sx = *src_x, sz = *src_z;

    // Receiver ownership (thread r handles receiver r).
    bool rOwn = false; int rIdx = 0;
    if (tid < NRECd) {
        int rx = rec_x[tid], rz = rec_z[tid];
        rOwn = (rx >= gx0 && rx < gx0 + TIk && rz >= gz0 && rz < gz0 + TIk);
        rIdx = (rx - gx0 + TBk) * EXTk + (rz - gz0 + TBk);
    }

    // Exact cone skip: cross stencil spreads <=1 L1-cell/step, source first
    // appears at step 0, so field@t is 0 beyond L1 radius t. Max t this
    // launch = t0+15; skip if ext region farther than t0+17 (margin 2).
    {
        int dxm = max(0, max(ox - sx, sx - (ox + EXTk - 1)));
        int dzm = max(0, max(oz - sz, sz - (oz + EXTk - 1)));
        if (dxm + dzm > t0 + TBk + 1) {
            if (rOwn) {
                #pragma unroll
                for (int s = 0; s < TBk; ++s)
                    out[tid * NSTEPSd + t0 + s] = 0.0f;
            }
            return;  // block-uniform: no barrier crossed
        }
    }

    // ---- Load phase: 16 cells/thread, column ez, rows r0+4i ----
    const int gz = oz + ez;
    const bool zin = (gz >= 0 && gz < NZd);
    float rCur[16], rOld[16], rV2[16];
    #pragma unroll
    for (int i = 0; i < 16; ++i) {
        const int ex = r0 + 4 * i;
        const int gx = ox + ex;
        float c = 0.0f, o = 0.0f, v2 = 0.0f;
        if (zin && gx >= 0 && gx < NXd) {
            const int g = gx * NZd + gz;
            c = Gc_in[g];
            o = Go_in[g];
            const float v = vel[g];
            v2 = v * v * DT2f;
        }
        rCur[i] = c; rOld[i] = o; rV2[i] = v2;
        sb[0][ex * EXTk + ez] = c;
        sb[1][ex * EXTk + ez] = c;  // out-of-domain cells must read 0 in both
    }

    // Source preload (only the owning thread's registers matter).
    const int exs = sx - ox, ezs = sz - oz;
    const bool srcHere = (exs >= 0 && exs < EXTk && ezs >= 0 && ezs < EXTk) &&
                         (tid == (((exs & 3) << 6) | ezs));
    float sv[TBk];
    if (srcHere) {
        #pragma unroll
        for (int s = 0; s < TBk; ++s) sv[s] = source[t0 + s] * DT2f;
    }

    __syncthreads();

    // ---- 16 sub-steps ----
    for (int s = 0; s < TBk; ++s) {
        const float* cur = sb[s & 1];
        float* nxt = sb[(s & 1) ^ 1];
        const int m = s + 1;                 // valid region [m, 64-m)
        const bool zv = zin && (ez >= m) && (ez < EXTk - m);
        #pragma unroll
        for (int i = 0; i < 16; ++i) {
            const int ex = r0 + 4 * i;
            const int gx = ox + ex;
            if (zv && ex >= m && ex < EXTk - m && gx >= 0 && gx < NXd) {
                const float up = cur[(ex - 1) * EXTk + ez];
                const float dn = cur[(ex + 1) * EXTk + ez];
                const float lf = cur[ex * EXTk + ez - 1];
                const float rt = cur[ex * EXTk + ez + 1];
                const float lap = (up + dn + lf + rt - 4.0f * rCur[i]) * INVf;
                const float nv = 2.0f * rCur[i] - rOld[i] + rV2[i] * lap;
                rOld[i] = rCur[i];
                rCur[i] = nv;
                nxt[ex * EXTk + ez] = nv;
            }
        }
        // Source injection (post-stencil, pre-recording), if src cell valid.
        if (srcHere && exs >= m && exs < EXTk - m && ezs >= m && ezs < EXTk - m) {
            #pragma unroll
            for (int i = 0; i < 16; ++i) {
                if (i == (exs >> 2)) {
                    rCur[i] += sv[s];
                    nxt[exs * EXTk + ezs] = rCur[i];
                }
            }
        }
        __syncthreads();
        // Receiver sampling of field@t0+s (post-injection).
        if (rOwn) out[tid * NSTEPSd + t0 + s] = nxt[rIdx];
        // next iter writes into cur (no one still reads it: pre-barrier), and
        // reads nxt (receiver reads are also reads) -> one barrier suffices.
    }

    // ---- Store back interior: rCur=field@t0+15, rOld=field@t0+14 ----
    if (ez >= TBk && ez < EXTk - TBk) {
        #pragma unroll
        for (int i = 4; i < 12; ++i) {       // ex = r0+4i in [16,48)
            const int ex = r0 + 4 * i;
            const int g = (ox + ex) * NZd + gz;
            Gc_out[g] = rCur[i];
            Go_out[g] = rOld[i];
        }
    }
}

extern "C" void kernel_launch(void* const* d_in, const int* in_sizes, int n_in,
                              void* d_out, int out_size, void* d_ws, size_t ws_size,
                              hipStream_t stream) {
    const float* vel    = (const float*)d_in[0];
    const float* source = (const float*)d_in[1];
    const int*   src_x  = (const int*)d_in[2];
    const int*   src_z  = (const int*)d_in[3];
    const int*   rec_x  = (const int*)d_in[4];
    const int*   rec_z  = (const int*)d_in[5];
    float* out = (float*)d_out;

    const size_t F = (size_t)NXd * NZd;
    float* A_c = (float*)d_ws;
    float* A_o = A_c + F;
    float* B_c = A_o + F;
    float* B_o = B_c + F;

    // Zero both ping-pong sets (ws is re-poisoned before every timed call).
    hipMemsetAsync(d_ws, 0, 4 * F * sizeof(float), stream);

    dim3 grid(NTILEk, NTILEk), block(256);
    for (int k = 0; k < NSTEPSd / TBk; ++k) {
        const float *ic, *io; float *oc, *oo;
        if (k & 1) { ic = B_c; io = B_o; oc = A_c; oo = A_o; }
        else       { ic = A_c; io = A_o; oc = B_c; oo = B_o; }
        fdtd_tblock<<<grid, block, 0, stream>>>(vel, source, src_x, src_z,
                                                rec_x, rec_z, ic, io, oc, oo,
                                                out, k * TBk);
    }
}

// Round 4
// 415.047 us; speedup vs baseline: 3.2373x; 2.3021x over previous
//
#include <hip/hip_runtime.h>

// WaveFDTD2D, temporally-blocked: T=16 steps/launch, 32 launches.
// Round 4: 1024-thread blocks (4 cells/thread, 16 waves/CU = 4/SIMD for
// latency hiding; round 3 had 1 wave/SIMD and ran ~6x above the LDS
// throughput floor). Domain-bounds checks removed from the hot loop:
// out-of-domain cells have v2=0, cur=old=0 so the update self-maintains
// zero (zero BC) -- only the trapezoid check remains, and its ex-part is
// wave-uniform (r0 = tid>>6). Substeps fully unrolled.

#define NXd 512
#define NZd 512
#define NSTEPSd 512
#define NRECd 128
#define DT2f 1.0e-6f
#define INVf 1.0e-2f
#define TBk 16           // temporal block (steps per launch)
#define TIk 32           // tile interior
#define EXTk 64          // TIk + 2*TBk
#define NTILEk 16        // NXd / TIk

__global__ __launch_bounds__(1024) void fdtd_tblock(
    const float* __restrict__ vel,
    const float* __restrict__ source,
    const int* __restrict__ src_x, const int* __restrict__ src_z,
    const int* __restrict__ rec_x, const int* __restrict__ rec_z,
    const float* __restrict__ Gc_in, const float* __restrict__ Go_in,
    float* __restrict__ Gc_out, float* __restrict__ Go_out,
    float* __restrict__ out, int t0)
{
    __shared__ float sb[2][EXTk * EXTk];

    const int tid = threadIdx.x;
    const int r0 = tid >> 6;        // 0..15: wave index (wave-uniform)
    const int ez = tid & 63;        // lane -> ext z coord
    const int gx0 = blockIdx.y * TIk, gz0 = blockIdx.x * TIk;
    const int ox = gx0 - TBk, oz = gz0 - TBk;

    const int sx = *src_x, sz = *src_z;

    // Receiver ownership (thread r handles receiver r).
    bool rOwn = false; int rIdx = 0;
    if (tid < NRECd) {
        int rx = rec_x[tid], rz = rec_z[tid];
        rOwn = (rx >= gx0 && rx < gx0 + TIk && rz >= gz0 && rz < gz0 + TIk);
        rIdx = (rx - gx0 + TBk) * EXTk + (rz - gz0 + TBk);
    }

    // Exact cone skip: cross stencil spreads <=1 L1-cell/step; field@t is
    // identically 0 beyond L1 radius t from the source. Max t this launch
    // = t0+15; skip if ext region farther than t0+17 (margin 2).
    {
        int dxm = max(0, max(ox - sx, sx - (ox + EXTk - 1)));
        int dzm = max(0, max(oz - sz, sz - (oz + EXTk - 1)));
        if (dxm + dzm > t0 + TBk + 1) {
            if (rOwn) {
                #pragma unroll
                for (int s = 0; s < TBk; ++s)
                    out[tid * NSTEPSd + t0 + s] = 0.0f;
            }
            return;  // block-uniform: no barrier crossed
        }
    }

    // ---- Load phase: 4 cells/thread, column ez, rows ex = r0 + 16*i ----
    const int gz = oz + ez;
    const bool zin = (gz >= 0 && gz < NZd);
    float rCur[4], rOld[4], rV2[4];
    #pragma unroll
    for (int i = 0; i < 4; ++i) {
        const int ex = r0 + 16 * i;
        const int gx = ox + ex;
        float c = 0.0f, o = 0.0f, v2 = 0.0f;
        if (zin && gx >= 0 && gx < NXd) {
            const int g = gx * NZd + gz;
            c = Gc_in[g];
            o = Go_in[g];
            const float v = vel[g];
            v2 = v * v * DT2f;
        }
        rCur[i] = c; rOld[i] = o; rV2[i] = v2;
        sb[0][ex * EXTk + ez] = c;
        sb[1][ex * EXTk + ez] = c;  // out-of-domain cells read 0 in both
    }

    // Source preload (owning thread only). Owner of ext cell (exs,ezs):
    // tid = ((exs & 15) << 6) | ezs, register index i = exs >> 4.
    const int exs = sx - ox, ezs = sz - oz;
    const bool srcHere = (exs >= 0 && exs < EXTk && ezs >= 0 && ezs < EXTk) &&
                         (tid == (((exs & 15) << 6) | ezs));
    float sv[TBk];
    if (srcHere) {
        #pragma unroll
        for (int s = 0; s < TBk; ++s) sv[s] = source[t0 + s] * DT2f;
    }

    __syncthreads();

    // ---- 16 sub-steps, fully unrolled (m and LDS pointers constant) ----
    #pragma unroll
    for (int s = 0; s < TBk; ++s) {
        const float* cur = sb[s & 1];
        float* nxt = sb[(s & 1) ^ 1];
        const int m = s + 1;                 // valid region [m, 64-m)
        const bool zv = (ez >= m) && (ez < EXTk - m);
        #pragma unroll
        for (int i = 0; i < 4; ++i) {
            const int ex = r0 + 16 * i;      // wave-uniform
            if (zv && ex >= m && ex < EXTk - m) {
                const float up = cur[(ex - 1) * EXTk + ez];
                const float dn = cur[(ex + 1) * EXTk + ez];
                const float lf = cur[ex * EXTk + ez - 1];
                const float rt = cur[ex * EXTk + ez + 1];
                const float lap = (up + dn + lf + rt - 4.0f * rCur[i]) * INVf;
                const float nv = 2.0f * rCur[i] - rOld[i] + rV2[i] * lap;
                rOld[i] = rCur[i];
                rCur[i] = nv;
                nxt[ex * EXTk + ez] = nv;
            }
        }
        // Source injection (post-stencil, pre-recording), if src cell valid.
        if (srcHere && exs >= m && exs < EXTk - m && ezs >= m && ezs < EXTk - m) {
            #pragma unroll
            for (int i = 0; i < 4; ++i) {
                if (i == (exs >> 4)) {
                    rCur[i] += sv[s];
                    nxt[exs * EXTk + ezs] = rCur[i];
                }
            }
        }
        __syncthreads();
        // Receiver sampling of field@t0+s (post-injection). Next iter writes
        // the OTHER buffer, so this read is race-free with one barrier.
        if (rOwn) out[tid * NSTEPSd + t0 + s] = nxt[rIdx];
    }

    // ---- Store interior: rCur=field@t0+15, rOld=field@t0+14 ----
    // Interior ex in [16,48) -> i = 1,2; always in-domain (grid aligned).
    if (ez >= TBk && ez < EXTk - TBk) {
        #pragma unroll
        for (int i = 1; i <= 2; ++i) {
            const int ex = r0 + 16 * i;
            const int g = (ox + ex) * NZd + gz;
            Gc_out[g] = rCur[i];
            Go_out[g] = rOld[i];
        }
    }
}

extern "C" void kernel_launch(void* const* d_in, const int* in_sizes, int n_in,
                              void* d_out, int out_size, void* d_ws, size_t ws_size,
                              hipStream_t stream) {
    const float* vel    = (const float*)d_in[0];
    const float* source = (const float*)d_in[1];
    const int*   src_x  = (const int*)d_in[2];
    const int*   src_z  = (const int*)d_in[3];
    const int*   rec_x  = (const int*)d_in[4];
    const int*   rec_z  = (const int*)d_in[5];
    float* out = (float*)d_out;

    const size_t F = (size_t)NXd * NZd;
    float* A_c = (float*)d_ws;
    float* A_o = A_c + F;
    float* B_c = A_o + F;
    float* B_o = B_c + F;

    // Zero both ping-pong sets (ws is re-poisoned before every timed call).
    hipMemsetAsync(d_ws, 0, 4 * F * sizeof(float), stream);

    dim3 grid(NTILEk, NTILEk), block(1024);
    for (int k = 0; k < NSTEPSd / TBk; ++k) {
        const float *ic, *io; float *oc, *oo;
        if (k & 1) { ic = B_c; io = B_o; oc = A_c; oo = A_o; }
        else       { ic = A_c; io = A_o; oc = B_c; oo = B_o; }
        fdtd_tblock<<<grid, block, 0, stream>>>(vel, source, src_x, src_z,
                                                rec_x, rec_z, ic, io, oc, oo,
                                                out, k * TBk);
    }
}

// Round 5
// 374.131 us; speedup vs baseline: 3.5914x; 1.1094x over previous
//
#include <hip/hip_runtime.h>

// WaveFDTD2D, temporally-blocked: T=16 steps/launch, 32 launches.
// Round 5: LDS-issue-bound fix (round 4 = 12.97 us/launch, exactly the
// 20-LDS-instr/substep issue model). Wave w owns 4 CONTIGUOUS rows
// (ex=4w..4w+3) at lane ez: z-neighbors via DPP wave shifts (VALU pipe),
// in-wave x-neighbors from registers, only 2 wave-boundary rows read from
// LDS. 6 LDS instr/thread/substep instead of 20. Trapezoid predication
// removed entirely: cone argument guarantees garbage never reaches
// interior/receivers; v2=0 pins out-of-domain cells to 0 (all garbage
// finite). Full nxt field still written so receiver gather stays simple.

#define NXd 512
#define NZd 512
#define NSTEPSd 512
#define NRECd 128
#define DT2f 1.0e-6f
#define INVf 1.0e-2f
#define TBk 16           // temporal block (steps per launch)
#define TIk 32           // tile interior
#define EXTk 64          // TIk + 2*TBk
#define NTILEk 16        // NXd / TIk

__device__ __forceinline__ float dpp_shr1(float x) {  // lane i <- lane i-1
    int v = __builtin_amdgcn_update_dpp(0, __builtin_bit_cast(int, x),
                                        0x138, 0xF, 0xF, false);  // WAVE_SHR:1
    return __builtin_bit_cast(float, v);
}
__device__ __forceinline__ float dpp_shl1(float x) {  // lane i <- lane i+1
    int v = __builtin_amdgcn_update_dpp(0, __builtin_bit_cast(int, x),
                                        0x130, 0xF, 0xF, false);  // WAVE_SHL:1
    return __builtin_bit_cast(float, v);
}

__global__ __launch_bounds__(1024) void fdtd_tblock(
    const float* __restrict__ vel,
    const float* __restrict__ source,
    const int* __restrict__ src_x, const int* __restrict__ src_z,
    const int* __restrict__ rec_x, const int* __restrict__ rec_z,
    const float* __restrict__ Gc_in, const float* __restrict__ Go_in,
    float* __restrict__ Gc_out, float* __restrict__ Go_out,
    float* __restrict__ out, int t0)
{
    __shared__ float sb[2][EXTk * EXTk];

    const int tid = threadIdx.x;
    const int w   = tid >> 6;       // wave 0..15: owns rows 4w..4w+3
    const int ez  = tid & 63;       // lane -> ext z coord
    const int gx0 = blockIdx.y * TIk, gz0 = blockIdx.x * TIk;
    const int ox = gx0 - TBk, oz = gz0 - TBk;

    const int sx = *src_x, sz = *src_z;

    // Receiver ownership (thread r handles receiver r, reads from LDS nxt).
    bool rOwn = false; int rIdx = 0;
    if (tid < NRECd) {
        int rx = rec_x[tid], rz = rec_z[tid];
        rOwn = (rx >= gx0 && rx < gx0 + TIk && rz >= gz0 && rz < gz0 + TIk);
        rIdx = (rx - gx0 + TBk) * EXTk + (rz - gz0 + TBk);
    }

    // Exact cone skip: cross stencil spreads <=1 L1-cell/step; field@t is
    // identically 0 beyond L1 radius t from the source.
    {
        int dxm = max(0, max(ox - sx, sx - (ox + EXTk - 1)));
        int dzm = max(0, max(oz - sz, sz - (oz + EXTk - 1)));
        if (dxm + dzm > t0 + TBk + 1) {
            if (rOwn) {
                #pragma unroll
                for (int s = 0; s < TBk; ++s)
                    out[tid * NSTEPSd + t0 + s] = 0.0f;
            }
            return;  // block-uniform: no barrier crossed
        }
    }

    // ---- Load: 4 contiguous rows/thread; v2 pre-folded with 1/(dx*dz) ----
    const int gz = oz + ez;
    const bool zin = (gz >= 0 && gz < NZd);
    float rCur[4], rOld[4], rV2i[4];
    #pragma unroll
    for (int i = 0; i < 4; ++i) {
        const int ex = 4 * w + i;
        const int gx = ox + ex;
        float c = 0.0f, o = 0.0f, v2 = 0.0f;
        if (zin && gx >= 0 && gx < NXd) {
            const int g = gx * NZd + gz;
            c = Gc_in[g];
            o = Go_in[g];
            const float v = vel[g];
            v2 = v * v * (DT2f * INVf);
        }
        rCur[i] = c; rOld[i] = o; rV2i[i] = v2;
        sb[0][ex * EXTk + ez] = c;   // only sb[0] needs prefill
    }
    // Wave-boundary row indices (clamped at ext edges; garbage there is
    // finite and never reaches interior -- cone argument).
    const int rowUp = (w == 0)  ? 0             : 4 * w - 1;
    const int rowDn = (w == 15) ? EXTk - 1      : 4 * w + 4;

    // Source preload (owner = lane ezs of wave exs>>2, register exs&3).
    const int exs = sx - ox, ezs = sz - oz;
    const bool srcHere = (exs >= 0 && exs < EXTk && ezs >= 0 && ezs < EXTk) &&
                         (tid == (((exs >> 2) << 6) | ezs));
    float sv[TBk];
    if (srcHere) {
        #pragma unroll
        for (int s = 0; s < TBk; ++s) sv[s] = source[t0 + s] * DT2f;
    }

    __syncthreads();

    // ---- 16 sub-steps, fully unrolled, no predication ----
    #pragma unroll
    for (int s = 0; s < TBk; ++s) {
        const float* cur = sb[s & 1];
        float* nxt = sb[(s & 1) ^ 1];
        const float up0 = cur[rowUp * EXTk + ez];   // ds_read_b32 x2 only
        const float dn3 = cur[rowDn * EXTk + ez];
        float nv[4];
        #pragma unroll
        for (int i = 0; i < 4; ++i) {
            const float up = (i == 0) ? up0 : rCur[i - 1];
            const float dn = (i == 3) ? dn3 : rCur[i + 1];
            const float lf = dpp_shr1(rCur[i]);     // z-1 neighbor (VALU)
            const float rt = dpp_shl1(rCur[i]);     // z+1 neighbor (VALU)
            const float sum = (up + dn) + (lf + rt);
            const float t4 = __builtin_fmaf(-4.0f, rCur[i], sum);
            const float pm = __builtin_fmaf(2.0f, rCur[i], -rOld[i]);
            nv[i] = __builtin_fmaf(rV2i[i], t4, pm);
        }
        #pragma unroll
        for (int i = 0; i < 4; ++i) {
            rOld[i] = rCur[i];
            rCur[i] = nv[i];
            nxt[(4 * w + i) * EXTk + ez] = nv[i];   // mergeable to write2
        }
        // Source injection (post-stencil, pre-recording), unconditional in s.
        if (srcHere) {
            #pragma unroll
            for (int i = 0; i < 4; ++i) {
                if (i == (exs & 3)) {
                    rCur[i] += sv[s];
                    nxt[exs * EXTk + ezs] = rCur[i];
                }
            }
        }
        __syncthreads();
        // Receiver sampling of field@t0+s (post-injection); next substep
        // writes the OTHER buffer, so one barrier suffices.
        if (rOwn) out[tid * NSTEPSd + t0 + s] = nxt[rIdx];
    }

    // ---- Store interior (rows 16..47 = waves 4..11, lanes 16..47) ----
    if (w >= 4 && w < 12 && ez >= TBk && ez < EXTk - TBk) {
        #pragma unroll
        for (int i = 0; i < 4; ++i) {
            const int g = (ox + 4 * w + i) * NZd + gz;
            Gc_out[g] = rCur[i];   // field @ t0+15
            Go_out[g] = rOld[i];   // field @ t0+14
        }
    }
}

extern "C" void kernel_launch(void* const* d_in, const int* in_sizes, int n_in,
                              void* d_out, int out_size, void* d_ws, size_t ws_size,
                              hipStream_t stream) {
    const float* vel    = (const float*)d_in[0];
    const float* source = (const float*)d_in[1];
    const int*   src_x  = (const int*)d_in[2];
    const int*   src_z  = (const int*)d_in[3];
    const int*   rec_x  = (const int*)d_in[4];
    const int*   rec_z  = (const int*)d_in[5];
    float* out = (float*)d_out;

    const size_t F = (size_t)NXd * NZd;
    float* A_c = (float*)d_ws;
    float* A_o = A_c + F;
    float* B_c = A_o + F;
    float* B_o = B_c + F;

    // Zero both ping-pong sets (ws is re-poisoned before every timed call).
    hipMemsetAsync(d_ws, 0, 4 * F * sizeof(float), stream);

    dim3 grid(NTILEk, NTILEk), block(1024);
    for (int k = 0; k < NSTEPSd / TBk; ++k) {
        const float *ic, *io; float *oc, *oo;
        if (k & 1) { ic = B_c; io = B_o; oc = A_c; oo = A_o; }
        else       { ic = A_c; io = A_o; oc = B_c; oo = B_o; }
        fdtd_tblock<<<grid, block, 0, stream>>>(vel, source, src_x, src_z,
                                                rec_x, rec_z, ic, io, oc, oo,
                                                out, k * TBk);
    }
}